// Round 1
// 2676.238 us; speedup vs baseline: 1.5441x; 1.5441x over previous
//
#include <hip/hip_runtime.h>

#define B_    512
#define L_    16
#define IN_   128
#define H_    1024
#define T_    64
#define OUTROW 10240   /* (L_+T_)*IN_ */

#define LDC   1040     /* c state fp32 row stride (padded) */
#define LDXL  144      /* XL fp32 row stride */
#define RSTRIDE 67     /* padded fp32 row stride in LDS reduction buffer */

/* ---- fragment-linear ("pre-swizzled") bf16 operand layout ----
   One fragment = 16 rows x 32 k-cols = 1024B, stored lane-linear so that one
   ld8 across a wave is a single CONTIGUOUS 1KB load (8 sequential 128B lines)
   instead of 16 scattered 64B requests:
     elem(row,k) @ u16 index  frag*512 + ((k&31)>>3)*128 + (row&15)*8 + (k&7)
     frag = (row>>4)*KH + (k>>5),  KH = K/32 (k-halves per rowgroup stripe)   */
#define KH_X  64   /* Xb   : 2048 cols (16 steps x 128) */
#define KH_H  32   /* H    : 1024 cols */
#define KH_XL 4    /* XLbf : 128 cols  */
#define KH_W0 36   /* W0c  : 1152 (4 x-kh + 32 h-kh) */
#define KH_W1 64   /* W1c  : 2048 */
#define KH_WO 32   /* Woutb: 1024 */

typedef __attribute__((ext_vector_type(8))) short bf8;
typedef __attribute__((ext_vector_type(4))) float f4;
typedef __attribute__((ext_vector_type(4))) unsigned short us4;
typedef unsigned short u16;
typedef unsigned int   u32;

#define MFMA16(a, b, c) __builtin_amdgcn_mfma_f32_16x16x32_bf16(a, b, c, 0, 0, 0)

__device__ __forceinline__ u16 f2bf(float f) {
    u32 u = __builtin_bit_cast(u32, f);
    u32 r = (u + 0x7fffu + ((u >> 16) & 1u)) >> 16;
    return (u16)r;
}
__device__ __forceinline__ float sigm(float x) { return 1.f / (1.f + __expf(-x)); }
__device__ __forceinline__ float tanh_f(float x) {
    float ax = fabsf(x);
    float e = __expf(-2.f * ax);
    float t = (1.f - e) / (1.f + e);
    return x < 0.f ? -t : t;
}
__device__ __forceinline__ bf8 ld8(const u16* p) { return *(const bf8*)p; }

__device__ __forceinline__ size_t swz(int kh_stride, int row, int k) {
    return ((size_t)(row >> 4) * kh_stride + (k >> 5)) * 512
           + ((k & 31) >> 3) * 128 + (row & 15) * 8 + (k & 7);
}

// 32-MFMA pack over one full K-tile (both 32-col halves)
#define MFMAT(AS, BS)                                                       \
  do {                                                                      \
    _Pragma("unroll")                                                       \
    for (int s_ = 0; s_ < 2; ++s_)                                          \
      _Pragma("unroll")                                                     \
      for (int g_ = 0; g_ < 4; ++g_)                                        \
        _Pragma("unroll")                                                   \
        for (int t_ = 0; t_ < 4; ++t_)                                      \
          acc[g_][t_] = MFMA16(AS[s_ * 4 + g_], BS[s_ * 4 + t_], acc[g_][t_]); \
  } while (0)

// Load one full K-tile (16 fully-coalesced 1KB fragment loads).
// KT = global k-tile index; A from concat(x-part, h-part).
#define LOADT_CELL(AS, BS, KT)                                              \
  do {                                                                      \
    const int kt_ = (KT);                                                   \
    const bool ix_ = kt_ < nk1;                                             \
    const int khA_ = (ix_ ? kt_ : kt_ - nk1) * 2;                           \
    const int khB_ = kt_ * 2;                                               \
    _Pragma("unroll")                                                       \
    for (int s_ = 0; s_ < 2; ++s_) {                                        \
      _Pragma("unroll")                                                     \
      for (int g_ = 0; g_ < 4; ++g_)                                        \
        AS[s_ * 4 + g_] = ld8((ix_ ? apx[g_] : aph[g_]) + (khA_ + s_) * 512); \
      _Pragma("unroll")                                                     \
      for (int t_ = 0; t_ < 4; ++t_)                                        \
        BS[s_ * 4 + t_] = ld8(bp[t_] + (khB_ + s_) * 512);                  \
    }                                                                       \
  } while (0)

#define LOADT_PROJ(AS, BS, KT)                                              \
  do {                                                                      \
    const int kh_ = (KT) * 2;                                               \
    _Pragma("unroll")                                                       \
    for (int s_ = 0; s_ < 2; ++s_) {                                        \
      _Pragma("unroll")                                                     \
      for (int g_ = 0; g_ < 4; ++g_)                                        \
        AS[s_ * 4 + g_] = ld8(ap[g_] + (kh_ + s_) * 512);                   \
      _Pragma("unroll")                                                     \
      for (int t_ = 0; t_ < 4; ++t_)                                        \
        BS[s_ * 4 + t_] = ld8(bp[t_] + (kh_ + s_) * 512);                   \
    }                                                                       \
  } while (0)

// ---- LSTM layer: 4-wave split-K GEMM (full-tile dual-buffered pipeline) +
// LDS reduction + fused cell epilogue. All bf16 operands fragment-linear.
// Grid 512: tn = (bid&7)*8 + ((bid>>3)&7), tm = bid>>6  (XCD-pins tn slice).
__global__ __launch_bounds__(256, 2) void cell_gemm(
    const u16* __restrict__ pA0, int kh0, int nk1,
    const u16* __restrict__ pA1, int kh1, int nk2,
    const u16* __restrict__ pB, int khB,
    const float* __restrict__ bias, float* __restrict__ Cst, u16* __restrict__ Hdst)
{
    __shared__ float red[4][64 * RSTRIDE];
    const int bid = blockIdx.x;
    const int tn = (bid & 7) * 8 + ((bid >> 3) & 7);
    const int tm = bid >> 6;
    const int tid = threadIdx.x;
    const int lane = tid & 63, ws = tid >> 6;
    const int l15 = lane & 15, qd = lane >> 4, q4 = qd * 4;

    // epilogue coords; prefetch the c RMW value NOW (hidden under whole GEMM)
    const int erow = ws * 16 + l15;
    const int grow = tm * 64 + erow;
    const int colb = tn * 16 + q4;
    const f4 cold = *(const f4*)&Cst[(size_t)grow * LDC + colb];

    f4 acc[4][4];
#pragma unroll
    for (int i = 0; i < 4; ++i)
#pragma unroll
        for (int j = 0; j < 4; ++j) acc[i][j] = (f4)(0.f);

    const u16* bp[4];
#pragma unroll
    for (int t = 0; t < 4; ++t)
        bp[t] = pB + (size_t)(tn * 4 + t) * khB * 512 + lane * 8;
    const u16* apx[4];
    const u16* aph[4];
#pragma unroll
    for (int g = 0; g < 4; ++g) {
        apx[g] = pA0 + (size_t)(tm * 4 + g) * kh0 * 512 + lane * 8;
        aph[g] = pA1 + (size_t)(tm * 4 + g) * kh1 * 512 + lane * 8;
    }

    const int nk  = nk1 + nk2;
    const int myn = (nk - ws + 3) >> 2;     // full K-tiles for this wave

    bf8 A0[8], B0[8], A1[8], B1[8];
    LOADT_CELL(A0, B0, ws);
    int i = 0, kt = ws;
    for (; i + 2 <= myn; i += 2, kt += 8) {
        LOADT_CELL(A1, B1, kt + 4);
        MFMAT(A0, B0);
        if (i + 2 < myn) LOADT_CELL(A0, B0, kt + 8);
        MFMAT(A1, B1);
    }
    if (i < myn) MFMAT(A0, B0);             // odd tail (already resident)

    // dump partials to padded LDS
#pragma unroll
    for (int rg = 0; rg < 4; ++rg)
#pragma unroll
        for (int t = 0; t < 4; ++t)
#pragma unroll
            for (int r = 0; r < 4; ++r)
                red[ws][(rg * 16 + q4 + r) * RSTRIDE + t * 16 + l15] = acc[rg][t][r];
    __syncthreads();

    // distributed epilogue: wave ws -> rows ws*16+l15; units u15 = q4..q4+3
    f4 gs[4];
#pragma unroll
    for (int G = 0; G < 4; ++G) {
        f4 s;
#pragma unroll
        for (int j = 0; j < 4; ++j) {
            const int cidx = erow * RSTRIDE + G * 16 + q4 + j;
            s[j] = red[0][cidx] + red[1][cidx] + red[2][cidx] + red[3][cidx];
        }
        gs[G] = s + *(const f4*)&bias[tn * 64 + G * 16 + q4];
    }
    f4 cn; us4 h4;
#pragma unroll
    for (int j = 0; j < 4; ++j) {
        const float I  = sigm(gs[0][j]);
        const float F  = sigm(gs[1][j]);
        const float Gg = tanh_f(gs[2][j]);
        const float O  = sigm(gs[3][j]);
        cn[j] = F * cold[j] + I * Gg;
        h4[j] = f2bf(O * tanh_f(cn[j]));
    }
    *(f4*)&Cst[(size_t)grow * LDC + colb] = cn;
    *(us4*)&Hdst[swz(KH_H, grow, colb)] = h4;
}

// ---- Output projection: 4-wave split-K (full-tile pipeline) + fused epilogue.
// Grid 16: tn = bid>>3, tm = bid&7. xl = xin + h1 @ Wout^T + b_out.
__global__ __launch_bounds__(256, 2) void proj_gemm(
    const u16* __restrict__ pA,   // H1 fragment-linear, KH_H
    const u16* __restrict__ pB,   // Woutb fragment-linear, KH_WO
    const float* __restrict__ bout,
    const float* __restrict__ xin, int ldxin,
    float* __restrict__ XL, u16* __restrict__ XLbf,
    float* __restrict__ dout, int slot)
{
    __shared__ float red[4][64 * RSTRIDE];
    const int bid = blockIdx.x;
    const int tn = bid >> 3, tm = bid & 7;
    const int tid = threadIdx.x;
    const int lane = tid & 63, ws = tid >> 6;
    const int l15 = lane & 15, qd = lane >> 4;

    f4 acc[4][4];
#pragma unroll
    for (int i = 0; i < 4; ++i)
#pragma unroll
        for (int j = 0; j < 4; ++j) acc[i][j] = (f4)(0.f);

    const u16* bp[4];
#pragma unroll
    for (int t = 0; t < 4; ++t)
        bp[t] = pB + (size_t)(tn * 4 + t) * KH_WO * 512 + lane * 8;
    const u16* ap[4];
#pragma unroll
    for (int g = 0; g < 4; ++g)
        ap[g] = pA + (size_t)(tm * 4 + g) * KH_H * 512 + lane * 8;

    const int myn = 4;   // 16 K-tiles / 4 waves
    bf8 A0[8], B0[8], A1[8], B1[8];
    LOADT_PROJ(A0, B0, ws);
    int i = 0, kt = ws;
    for (; i + 2 <= myn; i += 2, kt += 8) {
        LOADT_PROJ(A1, B1, kt + 4);
        MFMAT(A0, B0);
        if (i + 2 < myn) LOADT_PROJ(A0, B0, kt + 8);
        MFMAT(A1, B1);
    }

#pragma unroll
    for (int rg = 0; rg < 4; ++rg)
#pragma unroll
        for (int t = 0; t < 4; ++t)
#pragma unroll
            for (int r = 0; r < 4; ++r)
                red[ws][(rg * 16 + qd * 4 + r) * RSTRIDE + t * 16 + l15] = acc[rg][t][r];
    __syncthreads();

    const int erow = ws * 16 + l15;
    const int grow = tm * 64 + erow;
#pragma unroll
    for (int jb = 0; jb < 4; ++jb) {
        const int cin = qd * 16 + jb * 4;
        const int col = tn * 64 + cin;
        f4 s;
#pragma unroll
        for (int j2 = 0; j2 < 4; ++j2) {
            const int cidx = erow * RSTRIDE + cin + j2;
            s[j2] = red[0][cidx] + red[1][cidx] + red[2][cidx] + red[3][cidx];
        }
        const f4 v = *(const f4*)&xin[(size_t)grow * ldxin + col] + s
                     + *(const f4*)&bout[col];
        *(f4*)&XL[(size_t)grow * LDXL + col] = v;
        us4 b;
#pragma unroll
        for (int j2 = 0; j2 < 4; ++j2) b[j2] = f2bf(v[j2]);
        *(us4*)&XLbf[swz(KH_XL, grow, col)] = b;
        *(f4*)&dout[(size_t)grow * OUTROW + slot * IN_ + col] = v;
    }
}

// ---- Weight conversion: fp32 -> bf16 into fragment-linear layout, gate-
// permuted rows (p = (u>>4)*64 + G*16 + (u&15)), fused biases.
// One block per fragment: thread t writes u32 = 2 u16 at frag*256+t (coalesced).
__global__ void conv_w(const float* Wih0, const float* Whh0, const float* bih0, const float* bhh0,
                       const float* Wih1, const float* Whh1, const float* bih1, const float* bhh1,
                       const float* Wout,
                       u16* W0c, float* b0p, u16* W1c, float* b1p, u16* Woutb)
{
    const int bid = blockIdx.x, t = threadIdx.x;
    const int lane = t >> 2;              // fragment lane 0..63
    const int l15 = lane & 15, qd = lane >> 4;
    const int j0 = (t & 3) * 2;           // element pair within lane's 8
    const int c0_ = qd * 8 + j0;          // k within 32-col khalf

    if (bid < 9216) {                     // W0c: 256 rowgrps x 36 kh
        const int rg = bid / 36, kh = bid - rg * 36;
        const int p = rg * 16 + l15;
        const int rem = p & 63, G = rem >> 4, u = (p >> 6) * 16 + (rem & 15);
        const int src = G * H_ + u;
        float e0, e1;
        if (kh < 4) {
            e0 = Wih0[(size_t)src * IN_ + kh * 32 + c0_];
            e1 = Wih0[(size_t)src * IN_ + kh * 32 + c0_ + 1];
        } else {
            e0 = Whh0[(size_t)src * H_ + (kh - 4) * 32 + c0_];
            e1 = Whh0[(size_t)src * H_ + (kh - 4) * 32 + c0_ + 1];
        }
        ((u32*)W0c)[(size_t)bid * 256 + t] = (u32)f2bf(e0) | ((u32)f2bf(e1) << 16);
        if (kh == 0 && qd == 0 && j0 == 0) b0p[p] = bih0[src] + bhh0[src];
    } else if (bid < 25600) {             // W1c: 256 rowgrps x 64 kh
        const int x = bid - 9216;
        const int rg = x >> 6, kh = x & 63;
        const int p = rg * 16 + l15;
        const int rem = p & 63, G = rem >> 4, u = (p >> 6) * 16 + (rem & 15);
        const int src = G * H_ + u;
        float e0, e1;
        if (kh < 32) {
            e0 = Wih1[(size_t)src * H_ + kh * 32 + c0_];
            e1 = Wih1[(size_t)src * H_ + kh * 32 + c0_ + 1];
        } else {
            e0 = Whh1[(size_t)src * H_ + (kh - 32) * 32 + c0_];
            e1 = Whh1[(size_t)src * H_ + (kh - 32) * 32 + c0_ + 1];
        }
        ((u32*)W1c)[(size_t)x * 256 + t] = (u32)f2bf(e0) | ((u32)f2bf(e1) << 16);
        if (kh == 0 && qd == 0 && j0 == 0) b1p[p] = bih1[src] + bhh1[src];
    } else {                              // Woutb: 8 rowgrps x 32 kh
        const int x = bid - 25600;
        const int rg = x >> 5, kh = x & 31;
        const int r = rg * 16 + l15;
        const float e0 = Wout[(size_t)r * H_ + kh * 32 + c0_];
        const float e1 = Wout[(size_t)r * H_ + kh * 32 + c0_ + 1];
        ((u32*)Woutb)[(size_t)x * 256 + t] = (u32)f2bf(e0) | ((u32)f2bf(e1) << 16);
    }
}

// ---- Setup: zero states, x -> bf16 fragment-linear staging, x -> out[:,0:16] ----
__global__ void setup_k(const float* __restrict__ x, u16* __restrict__ Xb,
                        u16* H0, u16* H1, float* c0, float* c1,
                        float* __restrict__ dout)
{
    const int i = blockIdx.x * 256 + threadIdx.x;  // < 512*16*128 = 1048576
    const float v = x[i];
    const int r = i >> 11, col = i & 2047;
    Xb[swz(KH_X, r, col)] = f2bf(v);
    dout[(size_t)r * OUTROW + col] = v;
    if (i < B_ * H_) {
        H0[i] = 0; H1[i] = 0;              // H buffers are dense now
        const int rr = i >> 10, cc = i & 1023;
        c0[(size_t)rr * LDC + cc] = 0.f; c1[(size_t)rr * LDC + cc] = 0.f;
    }
}

extern "C" void kernel_launch(void* const* d_in, const int* in_sizes, int n_in,
                              void* d_out, int out_size, void* d_ws, size_t ws_size,
                              hipStream_t stream)
{
    const float* x    = (const float*)d_in[0];
    const float* Wih0 = (const float*)d_in[1];
    const float* Whh0 = (const float*)d_in[2];
    const float* bih0 = (const float*)d_in[3];
    const float* bhh0 = (const float*)d_in[4];
    const float* Wih1 = (const float*)d_in[5];
    const float* Whh1 = (const float*)d_in[6];
    const float* bih1 = (const float*)d_in[7];
    const float* bhh1 = (const float*)d_in[8];
    const float* Wout = (const float*)d_in[9];
    const float* bout = (const float*)d_in[10];
    float* dout = (float*)d_out;

    char* ws = (char*)d_ws;
    size_t off = 0;
    auto alloc = [&](size_t bytes) -> char* {
        char* p = ws + off; off += (bytes + 255) & ~(size_t)255; return p;
    };
    u16*  W0c   = (u16*)alloc((size_t)9216 * 1024);    // 256 rg x 36 kh frags
    u16*  W1c   = (u16*)alloc((size_t)16384 * 1024);   // 256 rg x 64 kh
    u16*  Woutb = (u16*)alloc((size_t)256 * 1024);     // 8 rg x 32 kh
    float* b0p  = (float*)alloc(4096 * 4);
    float* b1p  = (float*)alloc(4096 * 4);
    u16*  Xb    = (u16*)alloc((size_t)2048 * 1024);    // 32 rg x 64 kh
    u16*  H0b[2]; H0b[0] = (u16*)alloc((size_t)1024 * 1024); H0b[1] = (u16*)alloc((size_t)1024 * 1024);
    u16*  H1b[2]; H1b[0] = (u16*)alloc((size_t)1024 * 1024); H1b[1] = (u16*)alloc((size_t)1024 * 1024);
    float* c0   = (float*)alloc((size_t)B_ * LDC * 4);
    float* c1   = (float*)alloc((size_t)B_ * LDC * 4);
    float* XL   = (float*)alloc((size_t)B_ * LDXL * 4);
    u16*  XLbf  = (u16*)alloc((size_t)128 * 1024);     // 32 rg x 4 kh

    conv_w<<<25856, 256, 0, stream>>>(Wih0, Whh0, bih0, bhh0,
                                      Wih1, Whh1, bih1, bhh1, Wout,
                                      W0c, b0p, W1c, b1p, Woutb);
    setup_k<<<4096, 256, 0, stream>>>(x, Xb, H0b[0], H1b[0], c0, c1, dout);

    int p = 0;
    for (int g = 0; g < 79; ++g) {   // 16 prompt + 63 rollout stack steps
        const u16* xpart; int khx;
        if (g < 16) { xpart = Xb + (size_t)g * 2048; khx = KH_X; }
        else        { xpart = XLbf;                  khx = KH_XL; }
        cell_gemm<<<512, 256, 0, stream>>>(xpart, khx, 2, H0b[p], KH_H, 16,
                                           W0c, KH_W0, b0p, c0, H0b[1 - p]);
        cell_gemm<<<512, 256, 0, stream>>>(H0b[1 - p], KH_H, 16, H1b[p], KH_H, 16,
                                           W1c, KH_W1, b1p, c1, H1b[1 - p]);
        if (g >= 15) {
            const int s = g - 15;            // 0..63 -> out slot 16+s
            const float* xin; int ldxin;
            if (s == 0) { xin = x + 15 * IN_; ldxin = L_ * IN_; }
            else        { xin = XL;           ldxin = LDXL; }
            proj_gemm<<<16, 256, 0, stream>>>(H1b[1 - p], Woutb, bout,
                                              xin, ldxin, XL, XLbf, dout, 16 + s);
        }
        p ^= 1;
    }
}